// Round 1
// baseline (1674.995 us; speedup 1.0000x reference)
//
#include <hip/hip_runtime.h>
#include <math.h>

#define BB 128
#define SS 1024
#define MM 64
#define KDIM 128
#define VDIM 256
#define FDIM 128
#define QNUM 5000
#define QD 5001            // q ids 0..5000
#define RROWS (4 * QD)     // 20004 distinct (r,q) rows

#define QB 16                        // q's per EA block
#define NEA ((QD + QB - 1) / QB)     // 313 EA blocks
#define NPRE (NEA + QD + 128)        // total k_pre blocks

#define TW 64                        // timesteps per reduction window
#define NWIN (SS / TW)               // 16

typedef _Float16 half2_t __attribute__((ext_vector_type(2)));
typedef float f2 __attribute__((ext_vector_type(2)));
typedef _Float16 f16x8 __attribute__((ext_vector_type(8)));
typedef float f32x4 __attribute__((ext_vector_type(4)));
union U4 { uint4 u; half2_t h[4]; };

#if defined(__has_builtin)
#if __has_builtin(__builtin_elementwise_fma)
#define HAVE_EFMA 1
#endif
#endif

__device__ __forceinline__ f2 pkfma(f2 a, f2 b, f2 c) {
#ifdef HAVE_EFMA
  return __builtin_elementwise_fma(a, b, c);
#else
  f2 r; r.x = fmaf(a.x, b.x, c.x); r.y = fmaf(a.y, b.y, c.y); return r;
#endif
}

__device__ __forceinline__ float sigmoidf_(float x) { return 1.0f / (1.0f + expf(-x)); }
__device__ __forceinline__ float softplusf_(float x) { return (x > 20.0f) ? x : log1pf(expf(x)); }

// ---------------- K_PRE: fused EA(affine-in-r) + per-q tables + Wh transpose ----------------
__global__ __launch_bounds__(256) void k_pre(
    const float* __restrict__ Wv, const float* __restrict__ bv,
    const float* __restrict__ We, const float* __restrict__ be,
    const float* __restrict__ Wa, const float* __restrict__ ba,
    const float* __restrict__ q_embed, const float* __restrict__ key_mem,
    const float* __restrict__ W_summary, const float* __restrict__ b_summary,
    const float* __restrict__ W_disc,
    const float* __restrict__ W_beta, const float* __restrict__ b_beta,
    float2* __restrict__ EA, float* __restrict__ w_tab,
    float* __restrict__ Sq_tab, float* __restrict__ aq_tab,
    float* __restrict__ beta_tab, _Float16* __restrict__ Wh)
{
  const int tid = threadIdx.x;
  const int blk = blockIdx.x;
  __shared__ __align__(16) float smem[2 * QB * 256];           // 32 KB
  __shared__ float s_small[KDIM + MM + FDIM];                  // qe | slog | s_half

  if (blk < NEA) {
    float* su = smem;
    float* sd = smem + QB * 256;
    const int qbase = blk * QB;
#pragma unroll
    for (int j = 0; j < QB; ++j) {
      const int q = qbase + j;
      float u = bv[tid], d = 0.f;
      if (q >= 1 && q < QD) {
        u += Wv[(size_t)(q - 1) * VDIM + tid];
        d = Wv[(size_t)(QNUM + q - 1) * VDIM + tid] * (1.0f / 3.0f);
      }
      su[j * 256 + tid] = u;
      sd[j * 256 + tid] = d;
    }
    __syncthreads();
    f2 aB[QB], aD[QB];
#pragma unroll
    for (int j = 0; j < QB; ++j) { aB[j] = (f2){0.f, 0.f}; aD[j] = (f2){0.f, 0.f}; }
    for (int i = 0; i < 256; i += 4) {
      f2 w0, w1, w2, w3;
      w0.x = We[(i + 0) * VDIM + tid]; w0.y = Wa[(i + 0) * VDIM + tid];
      w1.x = We[(i + 1) * VDIM + tid]; w1.y = Wa[(i + 1) * VDIM + tid];
      w2.x = We[(i + 2) * VDIM + tid]; w2.y = Wa[(i + 2) * VDIM + tid];
      w3.x = We[(i + 3) * VDIM + tid]; w3.y = Wa[(i + 3) * VDIM + tid];
#pragma unroll
      for (int j = 0; j < QB; ++j) {
        const float4 uu = *(const float4*)&su[j * 256 + i];
        const float4 dd = *(const float4*)&sd[j * 256 + i];
        aB[j] = pkfma((f2){uu.x, uu.x}, w0, aB[j]);
        aD[j] = pkfma((f2){dd.x, dd.x}, w0, aD[j]);
        aB[j] = pkfma((f2){uu.y, uu.y}, w1, aB[j]);
        aD[j] = pkfma((f2){dd.y, dd.y}, w1, aD[j]);
        aB[j] = pkfma((f2){uu.z, uu.z}, w2, aB[j]);
        aD[j] = pkfma((f2){dd.z, dd.z}, w2, aD[j]);
        aB[j] = pkfma((f2){uu.w, uu.w}, w3, aB[j]);
        aD[j] = pkfma((f2){dd.w, dd.w}, w3, aD[j]);
      }
    }
    const float bev = be[tid], bav = ba[tid];
#pragma unroll
    for (int j = 0; j < QB; ++j) {
      const int q = qbase + j;
      if (q < QD) {
        const float pe0 = aB[j].x + bev, pa0 = aB[j].y + bav;
        const float de = aD[j].x, da = aD[j].y;
#pragma unroll
        for (int r = 0; r < 4; ++r) {
          float2 p;
          p.x = sigmoidf_(fmaf((float)r, de, pe0));
          p.y = tanhf(fmaf((float)r, da, pa0));
          EA[(size_t)(r * QD + q) * VDIM + tid] = p;
        }
      }
    }
  } else if (blk < NEA + QD) {
    const int q = blk - NEA;
    const int wave = tid >> 6, l = tid & 63;
    float* s_key  = smem;
    float* qe     = s_small;
    float* slog   = s_small + KDIM;
    float* s_half = s_small + KDIM + MM;
    for (int i = tid; i < MM * KDIM; i += 256) s_key[i] = key_mem[i];
    if (tid < KDIM) qe[tid] = q_embed[(size_t)q * KDIM + tid];
    __syncthreads();
    {
      const int m = tid >> 2, j = tid & 3;
      const float* krow = s_key + m * KDIM + j * 32;
      const float* qrow = qe + j * 32;
      float acc = 0.f;
#pragma unroll
      for (int k = 0; k < 32; ++k) {
        const int i = (k + tid) & 31;
        acc = fmaf(qrow[i], krow[i], acc);
      }
      acc += __shfl_xor(acc, 1);
      acc += __shfl_xor(acc, 2);
      if (j == 0) slog[m] = acc;
    }
    __syncthreads();
    if (wave == 0) {
      const float x = slog[l];
      float mx = x;
#pragma unroll
      for (int o = 32; o; o >>= 1) mx = fmaxf(mx, __shfl_xor(mx, o));
      const float e = expf(x - mx);
      float s = e;
#pragma unroll
      for (int o = 32; o; o >>= 1) s += __shfl_xor(s, o);
      w_tab[(size_t)q * MM + l] = e / s;
    } else if (wave == 1) {
      float p = qe[l] * W_disc[KDIM + l] + qe[64 + l] * W_disc[KDIM + 64 + l];
#pragma unroll
      for (int o = 32; o; o >>= 1) p += __shfl_xor(p, o);
      if (l == 0) aq_tab[q] = p;
    } else if (wave == 2) {
      float p0 = qe[l] * W_beta[l * 3 + 0] + qe[64 + l] * W_beta[(64 + l) * 3 + 0];
      float p1 = qe[l] * W_beta[l * 3 + 1] + qe[64 + l] * W_beta[(64 + l) * 3 + 1];
      float p2 = qe[l] * W_beta[l * 3 + 2] + qe[64 + l] * W_beta[(64 + l) * 3 + 2];
#pragma unroll
      for (int o = 32; o; o >>= 1) {
        p0 += __shfl_xor(p0, o); p1 += __shfl_xor(p1, o); p2 += __shfl_xor(p2, o);
      }
      if (l == 0) {
        beta_tab[(size_t)q * 3 + 0] = p0 + b_beta[0];
        beta_tab[(size_t)q * 3 + 1] = p1 + b_beta[1];
        beta_tab[(size_t)q * 3 + 2] = p2 + b_beta[2];
      }
    }
    {
      const int f = tid & 127, h = tid >> 7;
      float acc = 0.f;
#pragma unroll 8
      for (int k = 0; k < 64; ++k)
        acc = fmaf(qe[h * 64 + k], W_summary[(size_t)(VDIM + h * 64 + k) * FDIM + f], acc);
      if (h == 1) s_half[f] = acc;
      __syncthreads();
      if (h == 0) Sq_tab[(size_t)q * FDIM + f] = acc + s_half[f] + b_summary[f];
    }
  } else {
    const int e = (blk - NEA - QD) * 256 + tid;
    const int f = e >> 8, k = e & 255;
    Wh[(size_t)f * 256 + k] = (_Float16)W_summary[(size_t)k * FDIM + f];
  }
}

// ---------------- K3: k_rec7 — m-partitioned exact sequential recurrence ----------------
// Key fact: Mv[m] evolution is independent across m; only the read (sum over m)
// couples slots. 8 waves x 8 slots each run the exact recurrence over all 1024
// steps (3 FMA per (t,m) — the minimum), coupling via one LDS f32 atomicAdd per
// (t,lane) into a double-buffered partial buffer + a barrier every TW=64 steps.
// No accum passes, no D/U affine composition, no serial wave handoff.
struct W8 { f32x4 lo, hi; };

__global__ __launch_bounds__(512, 4) void k_rec7(
    const int* __restrict__ q_data, const int* __restrict__ r_data,
    const float* __restrict__ init_mv,
    const float2* __restrict__ EA, const float* __restrict__ w_tab,
    _Float16* __restrict__ Rd)
{
  const int tid = threadIdx.x;
  const int lane = tid & 63;
  const int wv = __builtin_amdgcn_readfirstlane(tid >> 6);   // wave id, force SGPR
  const int b = blockIdx.x >> 2, vc = blockIdx.x & 3;
  const int vv = vc * 64 + lane;                              // v within VDIM
  const int m0 = wv * 8;                                      // this wave's m slice

  __shared__ int s_pk[SS + 16];                               // (r*QD+q) | (q<<17)
  __shared__ __align__(16) float s_red[2][TW][64];            // partial-read buffers

  for (int i = tid; i < SS; i += 512) {
    const int q = q_data[b * SS + i];
    const int r = r_data[b * SS + i];
    s_pk[i] = (r * QD + q) | (q << 17);                       // row<2^15, q<2^13
  }
  if (tid < 16) s_pk[SS + tid] = 0;                           // safe pad for pipeline reads
  {
    f32x4* z = (f32x4*)&s_red[0][0][0];
    for (int i = tid; i < (2 * TW * 64) / 4; i += 512) z[i] = (f32x4){0.f, 0.f, 0.f, 0.f};
  }
  __syncthreads();

  float mv[8];
#pragma unroll
  for (int k = 0; k < 8; ++k) mv[k] = init_mv[(size_t)(m0 + k) * VDIM + vv];

  float2 eaA[4], eaB[4];
  W8 wA[4], wB[4];

  // Issue loads for one timestep: EA gather (per-lane v) + 8 w values
  // (wave-uniform -> SGPR base via readfirstlane; scalar/broadcast loads).
  auto ldissue = [&](int pv, float2* ea, W8* wreg) {
    const int pu = __builtin_amdgcn_readfirstlane(pv);
    const int ru = pu & 0x7FFF;                               // r*QD+q
    const int q64 = (pu >> 17) << 6;                          // q*64
    *ea = EA[(size_t)ru * VDIM + vv];
    const float* wp = w_tab + q64 + m0;                       // 32B aligned
    wreg->lo = *(const f32x4*)wp;
    wreg->hi = *(const f32x4*)(wp + 4);
  };

  // One timestep: rd += w*mv (pre-update), mv = fma(w, fma(-e,mv,a), mv)
  auto computeT = [&](float2 ea, W8 w, int buf, int tin) {
    const float e = ea.x, a = ea.y;
    float rd0, rd1;
    rd0 =      w.lo[0] * mv[0];        mv[0] = fmaf(w.lo[0], fmaf(-e, mv[0], a), mv[0]);
    rd1 =      w.lo[1] * mv[1];        mv[1] = fmaf(w.lo[1], fmaf(-e, mv[1], a), mv[1]);
    rd0 = fmaf(w.lo[2], mv[2], rd0);   mv[2] = fmaf(w.lo[2], fmaf(-e, mv[2], a), mv[2]);
    rd1 = fmaf(w.lo[3], mv[3], rd1);   mv[3] = fmaf(w.lo[3], fmaf(-e, mv[3], a), mv[3]);
    rd0 = fmaf(w.hi[0], mv[4], rd0);   mv[4] = fmaf(w.hi[0], fmaf(-e, mv[4], a), mv[4]);
    rd1 = fmaf(w.hi[1], mv[5], rd1);   mv[5] = fmaf(w.hi[1], fmaf(-e, mv[5], a), mv[5]);
    rd0 = fmaf(w.hi[2], mv[6], rd0);   mv[6] = fmaf(w.hi[2], fmaf(-e, mv[6], a), mv[6]);
    rd1 = fmaf(w.hi[3], mv[7], rd1);   mv[7] = fmaf(w.hi[3], fmaf(-e, mv[7], a), mv[7]);
    atomicAdd(&s_red[buf][tin][lane], rd0 + rd1);
  };

  // Software pipeline: ea/w prefetched 4 steps ahead (A/B halves), packed row
  // indices prefetched 8 steps ahead (pcl/pch cover [t0+4, t0+12)).
  int4 pcl, pch;
  {
    const int4 p0 = *(const int4*)&s_pk[0];
    pcl = *(const int4*)&s_pk[4];
    pch = *(const int4*)&s_pk[8];
    ldissue(p0.x, &eaA[0], &wA[0]);
    ldissue(p0.y, &eaA[1], &wA[1]);
    ldissue(p0.z, &eaA[2], &wA[2]);
    ldissue(p0.w, &eaA[3], &wA[3]);
  }

  int t0 = 0;
  for (int win = 0; win < NWIN; ++win) {
    const int buf = win & 1;
    for (int it = 0; it < TW / 8; ++it, t0 += 8) {
      const int4 pnl = *(const int4*)&s_pk[t0 + 12];
      const int4 pnh = *(const int4*)&s_pk[t0 + 16];
      const int tb = t0 & (TW - 1);
      // issue loads for [t0+4, t0+8)
      ldissue(pcl.x, &eaB[0], &wB[0]);
      ldissue(pcl.y, &eaB[1], &wB[1]);
      ldissue(pcl.z, &eaB[2], &wB[2]);
      ldissue(pcl.w, &eaB[3], &wB[3]);
      // compute [t0, t0+4)
      computeT(eaA[0], wA[0], buf, tb + 0);
      computeT(eaA[1], wA[1], buf, tb + 1);
      computeT(eaA[2], wA[2], buf, tb + 2);
      computeT(eaA[3], wA[3], buf, tb + 3);
      // issue loads for [t0+8, t0+12)
      ldissue(pch.x, &eaA[0], &wA[0]);
      ldissue(pch.y, &eaA[1], &wA[1]);
      ldissue(pch.z, &eaA[2], &wA[2]);
      ldissue(pch.w, &eaA[3], &wA[3]);
      // compute [t0+4, t0+8)
      computeT(eaB[0], wB[0], buf, tb + 4);
      computeT(eaB[1], wB[1], buf, tb + 5);
      computeT(eaB[2], wB[2], buf, tb + 6);
      computeT(eaB[3], wB[3], buf, tb + 7);
      pcl = pnl; pch = pnh;
    }
    __syncthreads();   // all adds for this window drained (lgkmcnt at barrier)
    {
      // reduce window: 512 threads x 8 values; store f16, re-zero buffer.
      const int j = tid >> 3;            // t within window
      const int v0 = (tid & 7) * 8;      // v chunk
      const f32x4 x0 = *(const f32x4*)&s_red[buf][j][v0];
      const f32x4 x1 = *(const f32x4*)&s_red[buf][j][v0 + 4];
      f16x8 h;
      h[0] = (_Float16)x0[0]; h[1] = (_Float16)x0[1];
      h[2] = (_Float16)x0[2]; h[3] = (_Float16)x0[3];
      h[4] = (_Float16)x1[0]; h[5] = (_Float16)x1[1];
      h[6] = (_Float16)x1[2]; h[7] = (_Float16)x1[3];
      *(f16x8*)&Rd[((size_t)b * SS + win * TW + j) * VDIM + vc * 64 + v0] = h;
      *(f32x4*)&s_red[buf][j][v0]     = (f32x4){0.f, 0.f, 0.f, 0.f};
      *(f32x4*)&s_red[buf][j][v0 + 4] = (f32x4){0.f, 0.f, 0.f, 0.f};
      // next adds to this buffer happen in window win+2, after win+1's barrier.
    }
  }
}

// ---------------- K4: summary GEMM via MFMA + heads + CORAL ----------------
__global__ __launch_bounds__(256) void k_head(
    const int* __restrict__ q_data,
    const _Float16* __restrict__ Rd, const _Float16* __restrict__ Wh,
    const float* __restrict__ Sq_tab, const float* __restrict__ aq_tab,
    const float* __restrict__ beta_tab,
    const float* __restrict__ W_theta, const float* __restrict__ b_theta,
    const float* __restrict__ W_disc, const float* __restrict__ b_disc,
    const float* __restrict__ W_c1, const float* __restrict__ b_c1,
    const float* __restrict__ W_c2, const float* __restrict__ b_c2,
    const float* __restrict__ coral_w, const float* __restrict__ coral_b,
    float* __restrict__ out)
{
  const int tid = threadIdx.x;
  const int w = tid >> 6, l = tid & 63;
  const int rowbase = blockIdx.x * 64;
  const int b = rowbase >> 10;
  const int t0 = rowbase & (SS - 1);

  __shared__ __align__(16) _Float16 s_A[64 * 256];   // 32 KB
  __shared__ __align__(16) _Float16 s_sum[64 * 128]; // 16 KB
  __shared__ __align__(16) float s_h1[4][64];
  __shared__ int   s_q[64];
  __shared__ float s_aq[64];
  __shared__ float s_be[64][3];

  {
    const uint4* src = (const uint4*)(Rd + (size_t)rowbase * VDIM);
    uint4* dst = (uint4*)s_A;
    for (int i = tid; i < (64 * 256 * 2) / 16; i += 256) dst[i] = src[i];
  }
  if (tid < 64) {
    const int q = q_data[b * SS + t0 + tid];
    s_q[tid] = q;
    s_aq[tid] = aq_tab[q];
    s_be[tid][0] = beta_tab[(size_t)q * 3 + 0];
    s_be[tid][1] = beta_tab[(size_t)q * 3 + 1];
    s_be[tid][2] = beta_tab[(size_t)q * 3 + 2];
  }
  __syncthreads();

  {
    const int quad = l >> 4, r16 = l & 15;
    const int mrow = w * 16 + r16;
    f32x4 acc[8];
#pragma unroll
    for (int nt = 0; nt < 8; ++nt) acc[nt] = (f32x4){0.f, 0.f, 0.f, 0.f};
#pragma unroll
    for (int ks = 0; ks < 8; ++ks) {
      const f16x8 afrag = *(const f16x8*)(s_A + mrow * 256 + ks * 32 + quad * 8);
#pragma unroll
      for (int nt = 0; nt < 8; ++nt) {
        const int n = nt * 16 + r16;
        const f16x8 bfrag = *(const f16x8*)(Wh + (size_t)n * 256 + ks * 32 + quad * 8);
        acc[nt] = __builtin_amdgcn_mfma_f32_16x16x32_f16(afrag, bfrag, acc[nt], 0, 0, 0);
      }
    }
#pragma unroll
    for (int nt = 0; nt < 8; ++nt) {
#pragma unroll
      for (int reg = 0; reg < 4; ++reg) {
        const int row = w * 16 + quad * 4 + reg;
        const int col = nt * 16 + r16;
        const float val = acc[nt][reg] + Sq_tab[(size_t)s_q[row] * FDIM + col];
        s_sum[row * 128 + col] = (_Float16)tanhf(val);
      }
    }
  }
  __syncthreads();

  const float tw0 = W_theta[l], tw1 = W_theta[64 + l], tb = b_theta[0];
  const float dw0 = W_disc[l], dw1 = W_disc[64 + l], db = b_disc[0];
  float wc1reg[5];
#pragma unroll
  for (int i = 0; i < 5; ++i) wc1reg[i] = W_c1[i * 64 + l];
  const float bc1 = b_c1[l];
  const int jj = l >> 1, hh2 = l & 1;
  float wc2reg[32];
#pragma unroll
  for (int i = 0; i < 32; ++i) wc2reg[i] = W_c2[(hh2 * 32 + i) * 32 + jj];
  const float bc2 = b_c2[jj];
  const float cw = coral_w[jj];
  const float cb0 = coral_b[0], cb1 = coral_b[1], cb2 = coral_b[2];

  float* out_theta = out;
  float* out_beta  = out + (size_t)BB * SS;
  float* out_alpha = out + (size_t)BB * SS * 4;
  float* out_probs = out + (size_t)BB * SS * 5;
  float* out_logit = out + (size_t)BB * SS * 9;

  for (int rr = 0; rr < 16; ++rr) {
    const int r = w * 16 + rr;
    const float su0 = (float)s_sum[r * 128 + l];
    const float su1 = (float)s_sum[r * 128 + 64 + l];
    float at = su0 * tw0 + su1 * tw1;
    float ad = su0 * dw0 + su1 * dw1;
#pragma unroll
    for (int o = 32; o; o >>= 1) { at += __shfl_xor(at, o); ad += __shfl_xor(ad, o); }
    const float theta = (at + tb) * 3.0f;
    const float alpha = softplusf_(ad + s_aq[r] + db);
    const float be0 = s_be[r][0], be1 = s_be[r][1], be2 = s_be[r][2];
    float h1 = bc1;
    h1 = fmaf(theta, wc1reg[0], h1);
    h1 = fmaf(alpha, wc1reg[1], h1);
    h1 = fmaf(be0, wc1reg[2], h1);
    h1 = fmaf(be1, wc1reg[3], h1);
    h1 = fmaf(be2, wc1reg[4], h1);
    h1 = fmaxf(h1, 0.f);
    s_h1[w][l] = h1;
    float hacc = hh2 ? 0.f : bc2;
    const float4* h4 = (const float4*)s_h1[w];
#pragma unroll
    for (int k = 0; k < 8; ++k) {
      const float4 hv = h4[(hh2 << 3) + k];
      hacc = fmaf(hv.x, wc2reg[4 * k + 0], hacc);
      hacc = fmaf(hv.y, wc2reg[4 * k + 1], hacc);
      hacc = fmaf(hv.z, wc2reg[4 * k + 2], hacc);
      hacc = fmaf(hv.w, wc2reg[4 * k + 3], hacc);
    }
    hacc += __shfl_xor(hacc, 1);
    const float h2 = fmaxf(hacc, 0.f);
    float p = h2 * cw * 0.5f;
#pragma unroll
    for (int o = 32; o; o >>= 1) p += __shfl_xor(p, o);
    if (l == 0) {
      const float z = p;
      const float l0 = z + cb0, l1 = z + cb1, l2 = z + cb2;
      const float s0 = sigmoidf_(l0), s1 = sigmoidf_(l1), s2 = sigmoidf_(l2);
      const float q0 = s0, q1 = s0 * s1, q2 = s0 * s1 * s2;
      const size_t bt = (size_t)rowbase + r;
      out_theta[bt] = theta;
      out_alpha[bt] = alpha;
      out_beta[bt * 3 + 0] = be0;
      out_beta[bt * 3 + 1] = be1;
      out_beta[bt * 3 + 2] = be2;
      out_logit[bt * 3 + 0] = l0;
      out_logit[bt * 3 + 1] = l1;
      out_logit[bt * 3 + 2] = l2;
      out_probs[bt * 4 + 0] = 1.f - q0;
      out_probs[bt * 4 + 1] = q0 - q1;
      out_probs[bt * 4 + 2] = q1 - q2;
      out_probs[bt * 4 + 3] = q2;
    }
  }
}

extern "C" void kernel_launch(void* const* d_in, const int* in_sizes, int n_in,
                              void* d_out, int out_size, void* d_ws, size_t ws_size,
                              hipStream_t stream) {
  const int*   q_data    = (const int*)d_in[0];
  const int*   r_data    = (const int*)d_in[1];
  const float* q_embed   = (const float*)d_in[2];
  const float* key_mem   = (const float*)d_in[3];
  const float* init_mv   = (const float*)d_in[4];
  const float* W_value   = (const float*)d_in[5];
  const float* b_value   = (const float*)d_in[6];
  const float* W_erase   = (const float*)d_in[7];
  const float* b_erase   = (const float*)d_in[8];
  const float* W_add     = (const float*)d_in[9];
  const float* b_add     = (const float*)d_in[10];
  const float* W_summary = (const float*)d_in[11];
  const float* b_summary = (const float*)d_in[12];
  const float* W_theta   = (const float*)d_in[13];
  const float* b_theta   = (const float*)d_in[14];
  const float* W_beta    = (const float*)d_in[15];
  const float* b_beta    = (const float*)d_in[16];
  const float* W_disc    = (const float*)d_in[17];
  const float* b_disc    = (const float*)d_in[18];
  const float* W_c1      = (const float*)d_in[19];
  const float* b_c1      = (const float*)d_in[20];
  const float* W_c2      = (const float*)d_in[21];
  const float* b_c2      = (const float*)d_in[22];
  const float* coral_w   = (const float*)d_in[23];
  const float* coral_b   = (const float*)d_in[24];

  float* ws = (float*)d_ws;
  size_t off = 0;
  float2* EA      = (float2*)(ws + off); off += (size_t)RROWS * VDIM * 2;
  float* w_tab    = ws + off; off += (size_t)QD * MM;
  float* Sq_tab   = ws + off; off += (size_t)QD * FDIM;
  float* aq_tab   = ws + off; off += 5120;
  float* beta_tab = ws + off; off += 15104;
  _Float16* Wh = (_Float16*)(ws + off); off += (VDIM * FDIM) / 2;
  _Float16* Rd = (_Float16*)(ws + off);

  k_pre<<<dim3(NPRE), dim3(256), 0, stream>>>(
      W_value, b_value, W_erase, b_erase, W_add, b_add,
      q_embed, key_mem, W_summary, b_summary, W_disc, W_beta, b_beta,
      EA, w_tab, Sq_tab, aq_tab, beta_tab, Wh);

  k_rec7<<<dim3(BB * 4), dim3(512), 0, stream>>>(
      q_data, r_data, init_mv, EA, w_tab, Rd);

  k_head<<<dim3((BB * SS) / 64), dim3(256), 0, stream>>>(
      q_data, Rd, Wh, Sq_tab, aq_tab, beta_tab,
      W_theta, b_theta, W_disc, b_disc,
      W_c1, b_c1, W_c2, b_c2, coral_w, coral_b, (float*)d_out);
}

// Round 2
// 532.113 us; speedup vs baseline: 3.1478x; 3.1478x over previous
//
#include <hip/hip_runtime.h>
#include <math.h>

#define BB 128
#define SS 1024
#define MM 64
#define KDIM 128
#define VDIM 256
#define FDIM 128
#define QNUM 5000
#define QD 5001            // q ids 0..5000
#define RROWS (4 * QD)     // 20004 distinct (r,q) rows

#define QB 16                        // q's per EA block
#define NEA ((QD + QB - 1) / QB)     // 313 EA blocks
#define NPRE (NEA + QD + 128)        // total k_pre blocks

#define TW 16                        // timesteps per reduction window
#define NWIN (SS / TW)               // 64

typedef _Float16 half2_t __attribute__((ext_vector_type(2)));
typedef float f2 __attribute__((ext_vector_type(2)));
typedef _Float16 f16x8 __attribute__((ext_vector_type(8)));
typedef float f32x4 __attribute__((ext_vector_type(4)));

#if defined(__has_builtin)
#if __has_builtin(__builtin_elementwise_fma)
#define HAVE_EFMA 1
#endif
#endif

__device__ __forceinline__ f2 pkfma(f2 a, f2 b, f2 c) {
#ifdef HAVE_EFMA
  return __builtin_elementwise_fma(a, b, c);
#else
  f2 r; r.x = fmaf(a.x, b.x, c.x); r.y = fmaf(a.y, b.y, c.y); return r;
#endif
}

__device__ __forceinline__ float sigmoidf_(float x) { return 1.0f / (1.0f + expf(-x)); }
__device__ __forceinline__ float softplusf_(float x) { return (x > 20.0f) ? x : log1pf(expf(x)); }

// ---------------- K_PRE: fused EA(affine-in-r) + per-q tables + Wh transpose ----------------
__global__ __launch_bounds__(256) void k_pre(
    const float* __restrict__ Wv, const float* __restrict__ bv,
    const float* __restrict__ We, const float* __restrict__ be,
    const float* __restrict__ Wa, const float* __restrict__ ba,
    const float* __restrict__ q_embed, const float* __restrict__ key_mem,
    const float* __restrict__ W_summary, const float* __restrict__ b_summary,
    const float* __restrict__ W_disc,
    const float* __restrict__ W_beta, const float* __restrict__ b_beta,
    float2* __restrict__ EA, float* __restrict__ w_tab,
    float* __restrict__ Sq_tab, float* __restrict__ aq_tab,
    float* __restrict__ beta_tab, _Float16* __restrict__ Wh)
{
  const int tid = threadIdx.x;
  const int blk = blockIdx.x;
  __shared__ __align__(16) float smem[2 * QB * 256];           // 32 KB
  __shared__ float s_small[KDIM + MM + FDIM];                  // qe | slog | s_half

  if (blk < NEA) {
    float* su = smem;
    float* sd = smem + QB * 256;
    const int qbase = blk * QB;
#pragma unroll
    for (int j = 0; j < QB; ++j) {
      const int q = qbase + j;
      float u = bv[tid], d = 0.f;
      if (q >= 1 && q < QD) {
        u += Wv[(size_t)(q - 1) * VDIM + tid];
        d = Wv[(size_t)(QNUM + q - 1) * VDIM + tid] * (1.0f / 3.0f);
      }
      su[j * 256 + tid] = u;
      sd[j * 256 + tid] = d;
    }
    __syncthreads();
    f2 aB[QB], aD[QB];
#pragma unroll
    for (int j = 0; j < QB; ++j) { aB[j] = (f2){0.f, 0.f}; aD[j] = (f2){0.f, 0.f}; }
    for (int i = 0; i < 256; i += 4) {
      f2 w0, w1, w2, w3;
      w0.x = We[(i + 0) * VDIM + tid]; w0.y = Wa[(i + 0) * VDIM + tid];
      w1.x = We[(i + 1) * VDIM + tid]; w1.y = Wa[(i + 1) * VDIM + tid];
      w2.x = We[(i + 2) * VDIM + tid]; w2.y = Wa[(i + 2) * VDIM + tid];
      w3.x = We[(i + 3) * VDIM + tid]; w3.y = Wa[(i + 3) * VDIM + tid];
#pragma unroll
      for (int j = 0; j < QB; ++j) {
        const float4 uu = *(const float4*)&su[j * 256 + i];
        const float4 dd = *(const float4*)&sd[j * 256 + i];
        aB[j] = pkfma((f2){uu.x, uu.x}, w0, aB[j]);
        aD[j] = pkfma((f2){dd.x, dd.x}, w0, aD[j]);
        aB[j] = pkfma((f2){uu.y, uu.y}, w1, aB[j]);
        aD[j] = pkfma((f2){dd.y, dd.y}, w1, aD[j]);
        aB[j] = pkfma((f2){uu.z, uu.z}, w2, aB[j]);
        aD[j] = pkfma((f2){dd.z, dd.z}, w2, aD[j]);
        aB[j] = pkfma((f2){uu.w, uu.w}, w3, aB[j]);
        aD[j] = pkfma((f2){dd.w, dd.w}, w3, aD[j]);
      }
    }
    const float bev = be[tid], bav = ba[tid];
#pragma unroll
    for (int j = 0; j < QB; ++j) {
      const int q = qbase + j;
      if (q < QD) {
        const float pe0 = aB[j].x + bev, pa0 = aB[j].y + bav;
        const float de = aD[j].x, da = aD[j].y;
#pragma unroll
        for (int r = 0; r < 4; ++r) {
          float2 p;
          p.x = sigmoidf_(fmaf((float)r, de, pe0));
          p.y = tanhf(fmaf((float)r, da, pa0));
          EA[(size_t)(r * QD + q) * VDIM + tid] = p;
        }
      }
    }
  } else if (blk < NEA + QD) {
    const int q = blk - NEA;
    const int wave = tid >> 6, l = tid & 63;
    float* s_key  = smem;
    float* qe     = s_small;
    float* slog   = s_small + KDIM;
    float* s_half = s_small + KDIM + MM;
    for (int i = tid; i < MM * KDIM; i += 256) s_key[i] = key_mem[i];
    if (tid < KDIM) qe[tid] = q_embed[(size_t)q * KDIM + tid];
    __syncthreads();
    {
      const int m = tid >> 2, j = tid & 3;
      const float* krow = s_key + m * KDIM + j * 32;
      const float* qrow = qe + j * 32;
      float acc = 0.f;
#pragma unroll
      for (int k = 0; k < 32; ++k) {
        const int i = (k + tid) & 31;
        acc = fmaf(qrow[i], krow[i], acc);
      }
      acc += __shfl_xor(acc, 1);
      acc += __shfl_xor(acc, 2);
      if (j == 0) slog[m] = acc;
    }
    __syncthreads();
    if (wave == 0) {
      const float x = slog[l];
      float mx = x;
#pragma unroll
      for (int o = 32; o; o >>= 1) mx = fmaxf(mx, __shfl_xor(mx, o));
      const float e = expf(x - mx);
      float s = e;
#pragma unroll
      for (int o = 32; o; o >>= 1) s += __shfl_xor(s, o);
      w_tab[(size_t)q * MM + l] = e / s;
    } else if (wave == 1) {
      float p = qe[l] * W_disc[KDIM + l] + qe[64 + l] * W_disc[KDIM + 64 + l];
#pragma unroll
      for (int o = 32; o; o >>= 1) p += __shfl_xor(p, o);
      if (l == 0) aq_tab[q] = p;
    } else if (wave == 2) {
      float p0 = qe[l] * W_beta[l * 3 + 0] + qe[64 + l] * W_beta[(64 + l) * 3 + 0];
      float p1 = qe[l] * W_beta[l * 3 + 1] + qe[64 + l] * W_beta[(64 + l) * 3 + 1];
      float p2 = qe[l] * W_beta[l * 3 + 2] + qe[64 + l] * W_beta[(64 + l) * 3 + 2];
#pragma unroll
      for (int o = 32; o; o >>= 1) {
        p0 += __shfl_xor(p0, o); p1 += __shfl_xor(p1, o); p2 += __shfl_xor(p2, o);
      }
      if (l == 0) {
        beta_tab[(size_t)q * 3 + 0] = p0 + b_beta[0];
        beta_tab[(size_t)q * 3 + 1] = p1 + b_beta[1];
        beta_tab[(size_t)q * 3 + 2] = p2 + b_beta[2];
      }
    }
    {
      const int f = tid & 127, h = tid >> 7;
      float acc = 0.f;
#pragma unroll 8
      for (int k = 0; k < 64; ++k)
        acc = fmaf(qe[h * 64 + k], W_summary[(size_t)(VDIM + h * 64 + k) * FDIM + f], acc);
      if (h == 1) s_half[f] = acc;
      __syncthreads();
      if (h == 0) Sq_tab[(size_t)q * FDIM + f] = acc + s_half[f] + b_summary[f];
    }
  } else {
    const int e = (blk - NEA - QD) * 256 + tid;
    const int f = e >> 8, k = e & 255;
    Wh[(size_t)f * 256 + k] = (_Float16)W_summary[(size_t)k * FDIM + f];
  }
}

// ---------------- K3: k_rec8 — m-partitioned recurrence, no atomics, no scalar loads ----------------
// 8 waves x 8 m-slots, exact sequential recurrence (3 FMA per (t,m) = the floor).
// Per 16-step window: per-wave partial reads ds_written to s_red[t][wave][lane],
// cross-wave reduced between two barriers. w rows double-buffer-staged in LDS via
// global->reg (issued at window start, ds_write in reduce phase); per-t w access
// is a wave-uniform broadcast ds_read_b128 x2, prefetched 2 steps ahead. EA is a
// per-lane dwordx2 gather in an 8-deep register ring. No SMEM, no LDS atomics.
__global__ __launch_bounds__(512, 4) void k_rec8(
    const int* __restrict__ q_data, const int* __restrict__ r_data,
    const float* __restrict__ init_mv,
    const float2* __restrict__ EA, const float* __restrict__ w_tab,
    _Float16* __restrict__ Rd)
{
  const int tid = threadIdx.x;
  const int lane = tid & 63;
  const int wv = tid >> 6;
  const int b = blockIdx.x >> 2, vc = blockIdx.x & 3;
  const int vv = vc * 64 + lane;                              // v within VDIM
  const int m0 = wv * 8;                                      // this wave's m slice

  __shared__ int s_off[SS + 32];                              // EA row byte offsets
  __shared__ int s_q64[SS + 32];                              // q*64 elem offsets in w_tab
  __shared__ __align__(16) float s_w[2][TW][64];              // staged w rows (dbuf)
  __shared__ __align__(16) float s_red[TW][8][64];            // per-wave read partials

  for (int i = tid; i < SS; i += 512) {
    const int q = q_data[b * SS + i];
    const int r = r_data[b * SS + i];
    s_off[i] = (r * QD + q) * (int)(VDIM * sizeof(float2));   // < 2^26, fits
    s_q64[i] = q << 6;
  }
  if (tid < 32) { s_off[SS + tid] = 0; s_q64[SS + tid] = 0; }
  __syncthreads();

  // stage window 0 of w synchronously (global -> reg -> LDS)
  {
    const float wa = w_tab[s_q64[wv] + lane];
    const float wb = w_tab[s_q64[wv + 8] + lane];
    s_w[0][wv][lane] = wa;
    s_w[0][wv + 8][lane] = wb;
  }

  float mv[8];
#pragma unroll
  for (int k = 0; k < 8; ++k) mv[k] = init_mv[(size_t)(m0 + k) * VDIM + vv];

  const char* EAv = (const char*)EA + (size_t)vv * sizeof(float2);

  __syncthreads();                                            // s_w[0] visible

  f2 ear[8];                                                  // EA ring, 8 deep
#pragma unroll
  for (int j = 0; j < 8; ++j)
    ear[j] = *(const f2*)(EAv + (size_t)(unsigned)s_off[j]);

  f32x4 wl[2], wh[2];                                         // w ring, 2 deep

  for (int win = 0; win < NWIN; ++win) {
    const int buf = win & 1;
    const int t0 = win * TW;
    // issue w-stage global loads for win+1 (latency hidden under this window)
    const int tn = ((win + 1) & (NWIN - 1)) * TW + wv;        // wraps harmlessly on last
    const float wstA = w_tab[s_q64[tn] + lane];
    const float wstB = w_tab[s_q64[tn + 8] + lane];
    // w regs for tt = 0,1 (broadcast ds_read)
    wl[0] = *(const f32x4*)&s_w[buf][0][m0];
    wh[0] = *(const f32x4*)&s_w[buf][0][m0 + 4];
    wl[1] = *(const f32x4*)&s_w[buf][1][m0];
    wh[1] = *(const f32x4*)&s_w[buf][1][m0 + 4];
#pragma unroll
    for (int tt = 0; tt < TW; ++tt) {
      const int t = t0 + tt;
      const f2 ea = ear[tt & 7];
      const f32x4 wlo = wl[tt & 1], whi = wh[tt & 1];
      if (tt < TW - 2) {                                      // prefetch w for tt+2
        wl[tt & 1] = *(const f32x4*)&s_w[buf][tt + 2][m0];
        wh[tt & 1] = *(const f32x4*)&s_w[buf][tt + 2][m0 + 4];
      }
      ear[tt & 7] = *(const f2*)(EAv + (size_t)(unsigned)s_off[t + 8]);  // EA for t+8
      const float e = ea.x, a = ea.y;
      float rd0, rd1;
      rd0 =      wlo[0] * mv[0];       mv[0] = fmaf(wlo[0], fmaf(-e, mv[0], a), mv[0]);
      rd1 =      wlo[1] * mv[1];       mv[1] = fmaf(wlo[1], fmaf(-e, mv[1], a), mv[1]);
      rd0 = fmaf(wlo[2], mv[2], rd0);  mv[2] = fmaf(wlo[2], fmaf(-e, mv[2], a), mv[2]);
      rd1 = fmaf(wlo[3], mv[3], rd1);  mv[3] = fmaf(wlo[3], fmaf(-e, mv[3], a), mv[3]);
      rd0 = fmaf(whi[0], mv[4], rd0);  mv[4] = fmaf(whi[0], fmaf(-e, mv[4], a), mv[4]);
      rd1 = fmaf(whi[1], mv[5], rd1);  mv[5] = fmaf(whi[1], fmaf(-e, mv[5], a), mv[5]);
      rd0 = fmaf(whi[2], mv[6], rd0);  mv[6] = fmaf(whi[2], fmaf(-e, mv[6], a), mv[6]);
      rd1 = fmaf(whi[3], mv[7], rd1);  mv[7] = fmaf(whi[3], fmaf(-e, mv[7], a), mv[7]);
      s_red[tt][wv][lane] = rd0 + rd1;                        // conflict-free ds_write
    }
    __syncthreads();                                          // barrier A: partials done
    {
      // land staged w for win+1 (vmcnt wait covered by the full window of compute)
      s_w[buf ^ 1][wv][lane] = wstA;
      s_w[buf ^ 1][wv + 8][lane] = wstB;
      // reduce TW x 64 outputs across 8 waves; store f16
      const int rt = tid >> 5;                                // 0..15
      const int vp = (tid & 31) * 2;                          // 0,2,..62
      f2 s = *(const f2*)&s_red[rt][0][vp];
#pragma unroll
      for (int k = 1; k < 8; ++k) s += *(const f2*)&s_red[rt][k][vp];
      half2_t hv; hv[0] = (_Float16)s.x; hv[1] = (_Float16)s.y;
      *(half2_t*)&Rd[((size_t)b * SS + t0 + rt) * VDIM + vc * 64 + vp] = hv;
    }
    __syncthreads();                                          // barrier B: s_red free, s_w ready
  }
}

// ---------------- K4: summary GEMM via MFMA + heads + CORAL ----------------
__global__ __launch_bounds__(256) void k_head(
    const int* __restrict__ q_data,
    const _Float16* __restrict__ Rd, const _Float16* __restrict__ Wh,
    const float* __restrict__ Sq_tab, const float* __restrict__ aq_tab,
    const float* __restrict__ beta_tab,
    const float* __restrict__ W_theta, const float* __restrict__ b_theta,
    const float* __restrict__ W_disc, const float* __restrict__ b_disc,
    const float* __restrict__ W_c1, const float* __restrict__ b_c1,
    const float* __restrict__ W_c2, const float* __restrict__ b_c2,
    const float* __restrict__ coral_w, const float* __restrict__ coral_b,
    float* __restrict__ out)
{
  const int tid = threadIdx.x;
  const int w = tid >> 6, l = tid & 63;
  const int rowbase = blockIdx.x * 64;
  const int b = rowbase >> 10;
  const int t0 = rowbase & (SS - 1);

  __shared__ __align__(16) _Float16 s_A[64 * 256];   // 32 KB
  __shared__ __align__(16) _Float16 s_sum[64 * 128]; // 16 KB
  __shared__ __align__(16) float s_h1[4][64];
  __shared__ int   s_q[64];
  __shared__ float s_aq[64];
  __shared__ float s_be[64][3];

  {
    const uint4* src = (const uint4*)(Rd + (size_t)rowbase * VDIM);
    uint4* dst = (uint4*)s_A;
    for (int i = tid; i < (64 * 256 * 2) / 16; i += 256) dst[i] = src[i];
  }
  if (tid < 64) {
    const int q = q_data[b * SS + t0 + tid];
    s_q[tid] = q;
    s_aq[tid] = aq_tab[q];
    s_be[tid][0] = beta_tab[(size_t)q * 3 + 0];
    s_be[tid][1] = beta_tab[(size_t)q * 3 + 1];
    s_be[tid][2] = beta_tab[(size_t)q * 3 + 2];
  }
  __syncthreads();

  {
    const int quad = l >> 4, r16 = l & 15;
    const int mrow = w * 16 + r16;
    f32x4 acc[8];
#pragma unroll
    for (int nt = 0; nt < 8; ++nt) acc[nt] = (f32x4){0.f, 0.f, 0.f, 0.f};
#pragma unroll
    for (int ks = 0; ks < 8; ++ks) {
      const f16x8 afrag = *(const f16x8*)(s_A + mrow * 256 + ks * 32 + quad * 8);
#pragma unroll
      for (int nt = 0; nt < 8; ++nt) {
        const int n = nt * 16 + r16;
        const f16x8 bfrag = *(const f16x8*)(Wh + (size_t)n * 256 + ks * 32 + quad * 8);
        acc[nt] = __builtin_amdgcn_mfma_f32_16x16x32_f16(afrag, bfrag, acc[nt], 0, 0, 0);
      }
    }
#pragma unroll
    for (int nt = 0; nt < 8; ++nt) {
#pragma unroll
      for (int reg = 0; reg < 4; ++reg) {
        const int row = w * 16 + quad * 4 + reg;
        const int col = nt * 16 + r16;
        const float val = acc[nt][reg] + Sq_tab[(size_t)s_q[row] * FDIM + col];
        s_sum[row * 128 + col] = (_Float16)tanhf(val);
      }
    }
  }
  __syncthreads();

  const float tw0 = W_theta[l], tw1 = W_theta[64 + l], tb = b_theta[0];
  const float dw0 = W_disc[l], dw1 = W_disc[64 + l], db = b_disc[0];
  float wc1reg[5];
#pragma unroll
  for (int i = 0; i < 5; ++i) wc1reg[i] = W_c1[i * 64 + l];
  const float bc1 = b_c1[l];
  const int jj = l >> 1, hh2 = l & 1;
  float wc2reg[32];
#pragma unroll
  for (int i = 0; i < 32; ++i) wc2reg[i] = W_c2[(hh2 * 32 + i) * 32 + jj];
  const float bc2 = b_c2[jj];
  const float cw = coral_w[jj];
  const float cb0 = coral_b[0], cb1 = coral_b[1], cb2 = coral_b[2];

  float* out_theta = out;
  float* out_beta  = out + (size_t)BB * SS;
  float* out_alpha = out + (size_t)BB * SS * 4;
  float* out_probs = out + (size_t)BB * SS * 5;
  float* out_logit = out + (size_t)BB * SS * 9;

  for (int rr = 0; rr < 16; ++rr) {
    const int r = w * 16 + rr;
    const float su0 = (float)s_sum[r * 128 + l];
    const float su1 = (float)s_sum[r * 128 + 64 + l];
    float at = su0 * tw0 + su1 * tw1;
    float ad = su0 * dw0 + su1 * dw1;
#pragma unroll
    for (int o = 32; o; o >>= 1) { at += __shfl_xor(at, o); ad += __shfl_xor(ad, o); }
    const float theta = (at + tb) * 3.0f;
    const float alpha = softplusf_(ad + s_aq[r] + db);
    const float be0 = s_be[r][0], be1 = s_be[r][1], be2 = s_be[r][2];
    float h1 = bc1;
    h1 = fmaf(theta, wc1reg[0], h1);
    h1 = fmaf(alpha, wc1reg[1], h1);
    h1 = fmaf(be0, wc1reg[2], h1);
    h1 = fmaf(be1, wc1reg[3], h1);
    h1 = fmaf(be2, wc1reg[4], h1);
    h1 = fmaxf(h1, 0.f);
    s_h1[w][l] = h1;
    float hacc = hh2 ? 0.f : bc2;
    const float4* h4 = (const float4*)s_h1[w];
#pragma unroll
    for (int k = 0; k < 8; ++k) {
      const float4 hv = h4[(hh2 << 3) + k];
      hacc = fmaf(hv.x, wc2reg[4 * k + 0], hacc);
      hacc = fmaf(hv.y, wc2reg[4 * k + 1], hacc);
      hacc = fmaf(hv.z, wc2reg[4 * k + 2], hacc);
      hacc = fmaf(hv.w, wc2reg[4 * k + 3], hacc);
    }
    hacc += __shfl_xor(hacc, 1);
    const float h2 = fmaxf(hacc, 0.f);
    float p = h2 * cw * 0.5f;
#pragma unroll
    for (int o = 32; o; o >>= 1) p += __shfl_xor(p, o);
    if (l == 0) {
      const float z = p;
      const float l0 = z + cb0, l1 = z + cb1, l2 = z + cb2;
      const float s0 = sigmoidf_(l0), s1 = sigmoidf_(l1), s2 = sigmoidf_(l2);
      const float q0 = s0, q1 = s0 * s1, q2 = s0 * s1 * s2;
      const size_t bt = (size_t)rowbase + r;
      out_theta[bt] = theta;
      out_alpha[bt] = alpha;
      out_beta[bt * 3 + 0] = be0;
      out_beta[bt * 3 + 1] = be1;
      out_beta[bt * 3 + 2] = be2;
      out_logit[bt * 3 + 0] = l0;
      out_logit[bt * 3 + 1] = l1;
      out_logit[bt * 3 + 2] = l2;
      out_probs[bt * 4 + 0] = 1.f - q0;
      out_probs[bt * 4 + 1] = q0 - q1;
      out_probs[bt * 4 + 2] = q1 - q2;
      out_probs[bt * 4 + 3] = q2;
    }
  }
}

extern "C" void kernel_launch(void* const* d_in, const int* in_sizes, int n_in,
                              void* d_out, int out_size, void* d_ws, size_t ws_size,
                              hipStream_t stream) {
  const int*   q_data    = (const int*)d_in[0];
  const int*   r_data    = (const int*)d_in[1];
  const float* q_embed   = (const float*)d_in[2];
  const float* key_mem   = (const float*)d_in[3];
  const float* init_mv   = (const float*)d_in[4];
  const float* W_value   = (const float*)d_in[5];
  const float* b_value   = (const float*)d_in[6];
  const float* W_erase   = (const float*)d_in[7];
  const float* b_erase   = (const float*)d_in[8];
  const float* W_add     = (const float*)d_in[9];
  const float* b_add     = (const float*)d_in[10];
  const float* W_summary = (const float*)d_in[11];
  const float* b_summary = (const float*)d_in[12];
  const float* W_theta   = (const float*)d_in[13];
  const float* b_theta   = (const float*)d_in[14];
  const float* W_beta    = (const float*)d_in[15];
  const float* b_beta    = (const float*)d_in[16];
  const float* W_disc    = (const float*)d_in[17];
  const float* b_disc    = (const float*)d_in[18];
  const float* W_c1      = (const float*)d_in[19];
  const float* b_c1      = (const float*)d_in[20];
  const float* W_c2      = (const float*)d_in[21];
  const float* b_c2      = (const float*)d_in[22];
  const float* coral_w   = (const float*)d_in[23];
  const float* coral_b   = (const float*)d_in[24];

  float* ws = (float*)d_ws;
  size_t off = 0;
  float2* EA      = (float2*)(ws + off); off += (size_t)RROWS * VDIM * 2;
  float* w_tab    = ws + off; off += (size_t)QD * MM;
  float* Sq_tab   = ws + off; off += (size_t)QD * FDIM;
  float* aq_tab   = ws + off; off += 5120;
  float* beta_tab = ws + off; off += 15104;
  _Float16* Wh = (_Float16*)(ws + off); off += (VDIM * FDIM) / 2;
  _Float16* Rd = (_Float16*)(ws + off);

  k_pre<<<dim3(NPRE), dim3(256), 0, stream>>>(
      W_value, b_value, W_erase, b_erase, W_add, b_add,
      q_embed, key_mem, W_summary, b_summary, W_disc, W_beta, b_beta,
      EA, w_tab, Sq_tab, aq_tab, beta_tab, Wh);

  k_rec8<<<dim3(BB * 4), dim3(512), 0, stream>>>(
      q_data, r_data, init_mv, EA, w_tab, Rd);

  k_head<<<dim3((BB * SS) / 64), dim3(256), 0, stream>>>(
      q_data, Rd, Wh, Sq_tab, aq_tab, beta_tab,
      W_theta, b_theta, W_disc, b_disc,
      W_c1, b_c1, W_c2, b_c2, coral_w, coral_b, (float*)d_out);
}